// Round 6
// baseline (167.645 us; speedup 1.0000x reference)
//
#include <hip/hip_runtime.h>

#define SLOT_B 10240                     // 10 cols x 1KB (512 bf16, swizzled grouped)
#define RING_B (8*SLOT_B)                // 8 row-slots = 81920
#define OROW_OFF RING_B
#define SMEM_T (RING_B + 16*512*4)       // + 16-pixel fp32 orow = 114688

typedef __attribute__((ext_vector_type(8))) short bf16x8;
typedef __attribute__((ext_vector_type(4))) float f32x4;
typedef __attribute__((ext_vector_type(2))) float f32x2;

__device__ __forceinline__ short f2bf(float f) {
  union { float f; unsigned u; } v; v.f = f;
  unsigned r = v.u + 0x7FFFu + ((v.u >> 16) & 1u);   // RNE
  return (short)(r >> 16);
}

__global__ __launch_bounds__(1024) void bconv_kernel(
    const float* __restrict__ x, const float* __restrict__ wts,
    const float* __restrict__ bias, const int* __restrict__ bin,
    const int* __restrict__ bout, float* __restrict__ out)
{
  extern __shared__ char smem[];
  float* orow = (float*)(smem + OROW_OFF);

  const int t = threadIdx.x, lane = t & 63, g = t >> 6;
  const int g4 = lane >> 4, n16 = lane & 15;
  const int bid = blockIdx.x;                 // 256 = b*16 + strip*2 + seg
  const int b = bid >> 4, strip = (bid >> 1) & 7, seg = bid & 1;
  const int hs = seg * 32, w0 = strip * 8;
  const int gbase = g * 64 + g4 * 16;

  // ---- inverse input-permutation: thread caches its 2 fixed channels ----
  unsigned short* pos_tab = (unsigned short*)(smem + OROW_OFF);  // transient in orow
  if (t < 512) pos_tab[bin[t]] = (unsigned short)t;
  __syncthreads();
  const int u = t & 255;                       // channel pair 2u, 2u+1
  const unsigned iv0 = pos_tab[2 * u];
  const unsigned iv1 = pos_tab[2 * u + 1];
  const int tq = t >> 8;                       // 0..3: column-task lane

  // ---- weight fragments (B elem j <-> ci = g4*8+j, kappa-consistent with A) ----
  bf16x8 wf[9][2];
  {
    const float* Wg = wts + g * 9216;
#pragma unroll
    for (int tap = 0; tap < 9; ++tap)
#pragma unroll
      for (int nt = 0; nt < 2; ++nt) {
        bf16x8 f;
#pragma unroll
        for (int j = 0; j < 8; ++j)
          f[j] = f2bf(Wg[(tap * 32 + g4 * 8 + j) * 32 + nt * 16 + n16]);
        wf[tap][nt] = f;
      }
  }
  // scatter targets: quad index XOR g4 (4-bank decorrelation across pixel rows)
  const int opos0 = bout[g * 32 + n16];
  const int opos1 = bout[g * 32 + 16 + n16];
  const int qb0 = (((opos0 >> 2) ^ g4) << 4) | ((opos0 & 3) << 2);
  const int qb1 = (((opos1 >> 2) ^ g4) << 4) | ((opos1 & 3) << 2);

  // flush constants: wave g owns pixel p=g (row h+(g>>3), col w0+(g&7))
  const int kp = g >> 2;                       // scatter key of this pixel
  const int lq = lane ^ kp;                    // permuted orow quad -> channels 4*lane
  const f32x4 bias0 = *(const f32x4*)(bias + lane * 4);
  const f32x4 bias1 = *(const f32x4*)(bias + 256 + lane * 4);

  // ---- prologue: stage rows hs-1..hs+2 (40 col-tasks, zero-fill OOB) ----
#pragma unroll
  for (int k = 0; k < 10; ++k) {
    const int tau = tq + 4 * k;                // 0..39
    const int rr_ = tau / 10;
    const int cs = tau - rr_ * 10;
    const int grow = hs - 1 + rr_;
    const int gcol = w0 - 1 + cs;
    f32x2 v = {0.f, 0.f};
    if (grow >= 0 && grow <= 63 && gcol >= 0 && gcol <= 63)
      v = *(const f32x2*)(x + (((size_t)(b * 64 + grow) * 64 + gcol) << 9) + 2 * u);
    char* sl = smem + (grow & 7) * SLOT_B + cs * 1024;
    const unsigned swz = (unsigned)((cs & 7) << 4);
    *(short*)(sl + ((iv0 * 2u) ^ swz)) = f2bf(v[0]);
    *(short*)(sl + ((iv1 * 2u) ^ swz)) = f2bf(v[1]);
  }
  asm volatile("s_waitcnt lgkmcnt(0)\ns_barrier" ::: "memory");

  const int m_r = n16 >> 3, m_c = n16 & 7;     // MFMA m -> (row, col) within tile

  for (int h = hs; h < hs + 32; h += 2) {
    // S1: issue staged loads for rows h+3, h+4 (5 x 8B per thread)
    f32x2 sv[5];
#pragma unroll
    for (int k = 0; k < 5; ++k) {
      const int tau = tq + 4 * k;              // 0..19
      const int cs = (tau < 10) ? tau : tau - 10;
      const int grow = h + 3 + (tau >= 10 ? 1 : 0);
      const int gcol = w0 - 1 + cs;
      f32x2 v = {0.f, 0.f};
      if (grow <= 63 && gcol >= 0 && gcol <= 63)
        v = *(const f32x2*)(x + (((size_t)(b * 64 + grow) * 64 + gcol) << 9) + 2 * u);
      sv[k] = v;
    }

    // S2: MFMA, 9 taps; A = one swizzled ds_read_b128, m = (2-row x 8-col) pixel
    f32x4 a0 = {0, 0, 0, 0}, a1 = {0, 0, 0, 0};
#pragma unroll
    for (int dh = 0; dh < 3; ++dh) {
      const char* rowp = smem + ((h + m_r + dh - 1) & 7) * SLOT_B;
#pragma unroll
      for (int dw = 0; dw < 3; ++dw) {
        const int cs = m_c + dw;
        const bf16x8 a = *(const bf16x8*)(rowp + cs * 1024 + (gbase ^ ((cs & 7) << 4)));
        a0 = __builtin_amdgcn_mfma_f32_16x16x32_bf16(a, wf[dh * 3 + dw][0], a0, 0, 0, 0);
        a1 = __builtin_amdgcn_mfma_f32_16x16x32_bf16(a, wf[dh * 3 + dw][1], a1, 0, 0, 0);
      }
    }
    asm volatile("s_waitcnt lgkmcnt(0)\ns_barrier" ::: "memory");   // barA

    // S4a: scatter D into orow (pixel = g4*4+rr; quad XORed by g4)
#pragma unroll
    for (int rr = 0; rr < 4; ++rr) {
      char* ob = (char*)orow + (g4 * 4 + rr) * 2048;
      *(float*)(ob + qb0) = a0[rr];
      *(float*)(ob + qb1) = a1[rr];
    }
    // S4b: staging writes for rows h+3, h+4 (skip beyond hs+32; row 64 = zeros)
#pragma unroll
    for (int k = 0; k < 5; ++k) {
      const int tau = tq + 4 * k;
      const int cs = (tau < 10) ? tau : tau - 10;
      const int grow = h + 3 + (tau >= 10 ? 1 : 0);
      if (grow <= hs + 32) {
        char* sl = smem + (grow & 7) * SLOT_B + cs * 1024;
        const unsigned swz = (unsigned)((cs & 7) << 4);
        *(short*)(sl + ((iv0 * 2u) ^ swz)) = f2bf(sv[k][0]);
        *(short*)(sl + ((iv1 * 2u) ^ swz)) = f2bf(sv[k][1]);
      }
    }
    asm volatile("s_waitcnt lgkmcnt(0)\ns_barrier" ::: "memory");   // barB

    // S6: flush pixel g, both rows-of-tile; each store = contiguous 1KB/instr
    {
      const float* oa = (const float*)((const char*)orow + g * 2048 + lq * 16);
      const f32x4 y0 = *(const f32x4*)oa;
      const f32x4 y1 = *(const f32x4*)(oa + 256);
      f32x4 o0, o1;
      o0[0] = fmaxf(y0[0] + bias0[0], 0.f); o0[1] = fmaxf(y0[1] + bias0[1], 0.f);
      o0[2] = fmaxf(y0[2] + bias0[2], 0.f); o0[3] = fmaxf(y0[3] + bias0[3], 0.f);
      o1[0] = fmaxf(y1[0] + bias1[0], 0.f); o1[1] = fmaxf(y1[1] + bias1[1], 0.f);
      o1[2] = fmaxf(y1[2] + bias1[2], 0.f); o1[3] = fmaxf(y1[3] + bias1[3], 0.f);
      float* dst = out + ((size_t)(b * 64 + h + (g >> 3)) * 64 + w0 + (g & 7)) * 512
                   + lane * 4;
      *(f32x4*)dst = o0;          // channels 4*lane      : contiguous 1KB per instr
      *(f32x4*)(dst + 256) = o1;  // channels 256+4*lane  : contiguous 1KB per instr
    }
    // stores drain under next iteration's S1/S2 (no vmcnt at barriers)
  }
}

extern "C" void kernel_launch(void* const* d_in, const int* in_sizes, int n_in,
                              void* d_out, int out_size, void* d_ws, size_t ws_size,
                              hipStream_t stream) {
  const float* x    = (const float*)d_in[0];
  const float* wts  = (const float*)d_in[1];
  const float* bias = (const float*)d_in[2];
  const int*   bin  = (const int*)d_in[3];
  const int*   bout = (const int*)d_in[4];
  float* out = (float*)d_out;
  (void)in_sizes; (void)n_in; (void)out_size; (void)d_ws; (void)ws_size;

  bconv_kernel<<<dim3(256), dim3(1024), SMEM_T, stream>>>(x, wts, bias, bin, bout, out);
}